// Round 7
// baseline (223.398 us; speedup 1.0000x reference)
//
#include <hip/hip_runtime.h>
#include <hip/hip_bf16.h>
#include <cstdint>
#include <cstddef>

// YatAttention on MI355X (gfx950).
// B=2, L=2048, E=768, H=12, D=64. GEMMs in bf16 MFMA 16x16x32 (fp32 accum).
// R9: occupancy play. R7/R8 proved in-loop op trims are null -> kernel is
// stall-bound at 3 blocks/CU (LDS 41984 caps residency; no pipe saturated).
// Cut LDS to 32768 = EXACTLY 5 blocks/CU (20 waves):
//  (1) lP restride 72->64 + 16B-chunk XOR swizzle (9216->8192B, also kills
//      the invariant 2.36M lP bank conflicts);
//  (2) V single-buffer via T14 reg-staging: V(t+1) global->regs at tile top
//      (full tile of latency cover), ds_write after barrier1, barrier2 =
//      cheap lgkm drain. K stays glds16-dbuf (proven).
// __launch_bounds__(256,5) to force 5-wave/SIMD VGPR budget.

typedef __bf16 bf16_t;
typedef __bf16 bf16x8 __attribute__((ext_vector_type(8)));
typedef __bf16 bf16x4 __attribute__((ext_vector_type(4)));
typedef float floatx4 __attribute__((ext_vector_type(4)));

#define DEVI static __device__ __forceinline__

#define Bc 2
#define Lc 2048
#define Ec 768
#define Hc 12
#define Dc 64
#define N3c 2304
#define Mc 4096
#define ROWSc (Bc * Hc * Lc)  // 49152

DEVI void glds16(const bf16_t* g, bf16_t* l) {
  __builtin_amdgcn_global_load_lds(
      (const __attribute__((address_space(1))) void*)g,
      (__attribute__((address_space(3))) void*)l, 16, 0, 0);
}

// ---------------- fused prep: fp32->bf16 cvt + two weight transposes -------
__global__ __launch_bounds__(256) void k_prep(
    const float* __restrict__ x, bf16_t* __restrict__ xb,
    const float* __restrict__ Wqkv, bf16_t* __restrict__ WqT,
    const float* __restrict__ Wout, bf16_t* __restrict__ WoT) {
  __shared__ float tile[32][33];
  const int bid = blockIdx.x, tid = threadIdx.x;
  if (bid < 3072) {
    const int i = (bid * 256 + tid) * 4;
    float4 v = *(const float4*)(x + i);
    bf16x4 o;
    o[0] = (bf16_t)v.x; o[1] = (bf16_t)v.y; o[2] = (bf16_t)v.z; o[3] = (bf16_t)v.w;
    *(bf16x4*)(xb + i) = o;
    return;
  }
  const float* in; bf16_t* out; int C, local;
  if (bid < 4800) { local = bid - 3072; in = Wqkv; out = WqT; C = N3c; }
  else            { local = bid - 4800; in = Wout; out = WoT; C = Ec;  }
  const int R = Ec;
  const int nbx = C / 32;
  const int c0 = (local % nbx) * 32, r0 = (local / nbx) * 32;
  const int tx = tid & 31, ty = tid >> 5;
  #pragma unroll
  for (int i = 0; i < 32; i += 8)
    tile[ty + i][tx] = in[(size_t)(r0 + ty + i) * C + c0 + tx];
  __syncthreads();
  #pragma unroll
  for (int i = 0; i < 32; i += 8)
    out[(size_t)(c0 + ty + i) * R + r0 + tx] = (bf16_t)tile[tx][ty + i];
}

// ---------------- GEMM core (m97 pattern) ----------------

DEVI void gemm_core(const bf16_t* __restrict__ A, const bf16_t* __restrict__ Bt,
                    bf16_t* lA, bf16_t* lB, int m0, int n0, floatx4 (&acc)[4][4]) {
  const int tid = threadIdx.x, wave = tid >> 6, lane = tid & 63;
  const int wm = (wave >> 1) * 64, wn = (wave & 1) * 64;
  const int lrow = lane >> 2, lseg = lane & 3;
  const int quad = lane >> 4, r16 = lane & 15;
  for (int kk = 0; kk < 768; kk += 32) {
    glds16(A  + (size_t)(m0 + wave * 32      + lrow) * 768 + kk + lseg * 8, lA + (wave * 32) * 32);
    glds16(A  + (size_t)(m0 + wave * 32 + 16 + lrow) * 768 + kk + lseg * 8, lA + (wave * 32 + 16) * 32);
    glds16(Bt + (size_t)(n0 + wave * 32      + lrow) * 768 + kk + lseg * 8, lB + (wave * 32) * 32);
    glds16(Bt + (size_t)(n0 + wave * 32 + 16 + lrow) * 768 + kk + lseg * 8, lB + (wave * 32 + 16) * 32);
    __syncthreads();
    bf16x8 af[4], bv[4];
    #pragma unroll
    for (int mi = 0; mi < 4; mi++)
      af[mi] = *(const bf16x8*)(lA + (wm + mi * 16 + r16) * 32 + quad * 8);
    #pragma unroll
    for (int ni = 0; ni < 4; ni++)
      bv[ni] = *(const bf16x8*)(lB + (wn + ni * 16 + r16) * 32 + quad * 8);
    #pragma unroll
    for (int mi = 0; mi < 4; mi++)
      #pragma unroll
      for (int ni = 0; ni < 4; ni++)
        acc[mi][ni] = __builtin_amdgcn_mfma_f32_16x16x32_bf16(af[mi], bv[ni], acc[mi][ni], 0, 0, 0);
    __syncthreads();
  }
}

__global__ __launch_bounds__(256) void k_gemm_qkv(
    const bf16_t* __restrict__ A, const bf16_t* __restrict__ Bt,
    const float* __restrict__ bias,
    bf16_t* __restrict__ Qo, bf16_t* __restrict__ Ko, bf16_t* __restrict__ Vo) {
  __shared__ bf16_t lA[128 * 32];
  __shared__ bf16_t lB[128 * 32];
  const int m0 = blockIdx.y * 128, n0 = blockIdx.x * 128;
  const int tid = threadIdx.x, wave = tid >> 6, lane = tid & 63;
  const int wm = (wave >> 1) * 64, wn = (wave & 1) * 64;
  const int quad = lane >> 4, r16 = lane & 15;
  floatx4 acc[4][4] = {};
  gemm_core(A, Bt, lA, lB, m0, n0, acc);

  const int sec = n0 / 768;
  bf16_t* dst = (sec == 0) ? Qo : ((sec == 1) ? Ko : Vo);
  #pragma unroll
  for (int ni = 0; ni < 4; ni++) {
    const int n = n0 + wn + ni * 16 + r16;
    const int nn = n - sec * 768;
    const int h = nn >> 6, d = nn & 63;
    const float bvs = bias[n];
    #pragma unroll
    for (int mi = 0; mi < 4; mi++) {
      #pragma unroll
      for (int reg = 0; reg < 4; reg++) {
        const int m = m0 + wm + mi * 16 + quad * 4 + reg;
        const int b = m >> 11, l = m & 2047;
        const float v = acc[mi][ni][reg] + bvs;
        dst[(((size_t)(b * Hc + h)) * Lc + l) * Dc + d] = (bf16_t)v;
      }
    }
  }
}

__global__ __launch_bounds__(256) void k_gemm_out(
    const bf16_t* __restrict__ A, const bf16_t* __restrict__ Bt,
    const float* __restrict__ bias, float* __restrict__ out) {
  __shared__ bf16_t lA[128 * 32];
  __shared__ bf16_t lB[128 * 32];
  const int m0 = blockIdx.y * 128, n0 = blockIdx.x * 128;
  const int tid = threadIdx.x, wave = tid >> 6, lane = tid & 63;
  const int wm = (wave >> 1) * 64, wn = (wave & 1) * 64;
  const int quad = lane >> 4, r16 = lane & 15;
  floatx4 acc[4][4] = {};
  gemm_core(A, Bt, lA, lB, m0, n0, acc);
  #pragma unroll
  for (int ni = 0; ni < 4; ni++) {
    const int n = n0 + wn + ni * 16 + r16;
    const float bvs = bias[n];
    #pragma unroll
    for (int mi = 0; mi < 4; mi++) {
      #pragma unroll
      for (int reg = 0; reg < 4; reg++) {
        const int m = m0 + wm + mi * 16 + quad * 4 + reg;
        out[(size_t)m * Ec + n] = acc[mi][ni][reg] + bvs;
      }
    }
  }
}

// ------- fused prep2: q_sq/k_sq (+eps, mask bias) + V transpose -------
__global__ __launch_bounds__(256) void k_prep2(
    const bf16_t* __restrict__ Q, const bf16_t* __restrict__ K,
    const int* __restrict__ mask,
    float* __restrict__ qsq, float* __restrict__ ksq,
    float* __restrict__ mbias,
    const bf16_t* __restrict__ V, bf16_t* __restrict__ VT) {
  __shared__ bf16_t tb[64][72];
  const int bid = blockIdx.x, tid = threadIdx.x;
  if (bid < 192) {
    const int row = bid * 256 + tid;
    const bf16x8* q = (const bf16x8*)(Q + (size_t)row * 64);
    const bf16x8* k = (const bf16x8*)(K + (size_t)row * 64);
    float sq = 0.f, sk = 0.f;
    #pragma unroll
    for (int c = 0; c < 8; c++) {
      bf16x8 vq = q[c], vk = k[c];
      #pragma unroll
      for (int j = 0; j < 8; j++) {
        float a = (float)vq[j]; sq += a * a;
        float b = (float)vk[j]; sk += b * b;
      }
    }
    qsq[row] = sq;
    ksq[row] = sk + 1e-6f;
    const int bh = row >> 11, l = row & 2047;
    if (bh == 0 || bh == Hc) {
      const int b = bh / Hc;
      mbias[b * Lc + l] = (mask[b * Lc + l] == 1) ? 0.f : -1e30f;
    }
    return;
  }
  const int gid = bid - 192;
  const int bh = gid >> 5, j0 = (gid & 31) * 64;
  const bf16_t* Vh = V + ((size_t)bh * Lc) * Dc;
  bf16_t* VTh = VT + ((size_t)bh * Dc) * Lc;
  #pragma unroll
  for (int it = 0; it < 2; ++it) {
    int c = tid + it * 256;
    int j = c >> 3, seg = c & 7;
    *(bf16x8*)&tb[j][seg * 8] = *(const bf16x8*)(Vh + (size_t)(j0 + j) * 64 + seg * 8);
  }
  __syncthreads();
  #pragma unroll
  for (int it = 0; it < 2; ++it) {
    int c = tid + it * 256;
    int d = c >> 3, jseg = c & 7;
    bf16x8 o;
    #pragma unroll
    for (int u = 0; u < 8; u++) o[u] = tb[jseg * 8 + u][d];
    *(bf16x8*)(VTh + (size_t)d * Lc + j0 + jseg * 8) = o;
  }
}

// ---------------- flash attention: 32KB LDS -> 5 blocks/CU ----------------
// grid = 768. Block: 4 waves, 64 queries (wave = 16). Key tile = 64.
// K glds16 dbuf; V single-buffer (T14 reg-staged: global->reg at tile top,
// ds_write after barrier1, barrier2 = lgkm drain); lP stride-64 + 16B-chunk
// XOR swizzle. S^T = K.Q^T; O^T = VT.P^T; softmax per-lane (query = r16).
__global__ __launch_bounds__(256, 5) void k_attn(
    const bf16_t* __restrict__ Q, const bf16_t* __restrict__ K,
    const bf16_t* __restrict__ VT, const float* __restrict__ qsq,
    const float* __restrict__ ksq, const float* __restrict__ mbias,
    bf16_t* __restrict__ AO) {
  __shared__ bf16_t lK[2][4096];   // 64 keys x 64 d, swizzled 16B chunks (dbuf)
  __shared__ bf16_t lV[4096];      // 64 d x 64 keys, swizzled 16B chunks (single)
  __shared__ bf16_t lP[4][16 * 64];// per-wave P, stride 64, chunk-XOR swizzled
  const int gid0 = blockIdx.x;
  const int gid = (gid0 & 7) * 96 + (gid0 >> 3);  // XCD swizzle: 3 bh per XCD
  const int bh = gid >> 5, qt = gid & 31;
  const int b = bh / Hc;
  const int h = bh - b * Hc;
  const int tid = threadIdx.x, wave = tid >> 6, lane = tid & 63;
  const int quad = lane >> 4, r16 = lane & 15;
  const int q0 = qt * 64 + wave * 16;
  const bf16_t* Qh = Q + ((size_t)bh * Lc) * Dc;
  const bf16_t* Kh = K + ((size_t)bh * Lc) * Dc;
  const bf16_t* VTh = VT + ((size_t)bh * Dc) * Lc;
  const float* qsqh = qsq + bh * Lc;
  const float* ksqh = ksq + bh * Lc;
  const float* mbb = mbias + b * Lc;
  bf16_t* myP = &lP[wave][0];

  // staging geometry: chunk p = i*256 + wave*64 + lane covers row p>>3,
  // slot p&7 holding global chunk (p&7)^((p>>3)&7).
  const int p0 = wave * 64 + lane;
  const int srow = p0 >> 3;
  const int sj = (p0 & 7) ^ (srow & 7);
  const bf16_t* kg0 = Kh + (size_t)srow * 64 + sj * 8;
  const bf16_t* kg1 = kg0 + 32 * 64;
  const bf16_t* vg0 = VTh + (size_t)srow * Lc + sj * 8;
  const bf16_t* vg1 = vg0 + 32 * Lc;
  const int ld0 = wave * 64 * 8, ld1 = (256 + wave * 64) * 8;  // elements

  // K/V fragment read slots (swizzled)
  const int sl0 = ((quad ^ (r16 & 7)) * 8);
  const int sl1 = sl0 ^ 32;

  // lP swizzle: logical chunk j (8 elems) at j ^ (r16&7)
  const int pswz = r16 & 7;

  bf16x8 qf0 = *(const bf16x8*)(Qh + (size_t)(q0 + r16) * 64 + quad * 8);
  bf16x8 qf1 = *(const bf16x8*)(Qh + (size_t)(q0 + r16) * 64 + 32 + quad * 8);
  const float qs = qsqh[q0 + r16];
  float mi = -1e30f;        // LOG2 domain, shared across the query's 4 lanes
  float li = 0.f;           // per-lane partial; reduced in epilogue
  floatx4 of[4] = {};

  // prologue: stage K(0)->lK[0], V(0)->lV via glds; ks/mb for tile 0
  glds16(kg0, &lK[0][ld0]);
  glds16(kg1, &lK[0][ld1]);
  glds16(vg0, &lV[ld0]);
  glds16(vg1, &lV[ld1]);
  kg0 += 4096; kg1 += 4096; vg0 += 64; vg1 += 64;
  float4 ks4[4], mb4[4];
  #pragma unroll
  for (int c = 0; c < 4; c++) {
    ks4[c] = *(const float4*)(ksqh + c * 16 + quad * 4);
    mb4[c] = *(const float4*)(mbb + c * 16 + quad * 4);
  }
  __syncthreads();

  const int nt = Lc / 64;  // 32
  for (int t = 0; t < nt; t++) {
    const int cur = t & 1;
    const bool more = (t + 1 < nt);
    bf16x8 vr0, vr1;  // V(t+1) reg-staged
    if (more) {
      glds16(kg0, &lK[cur ^ 1][ld0]);
      glds16(kg1, &lK[cur ^ 1][ld1]);
      kg0 += 4096; kg1 += 4096;
      vr0 = *(const bf16x8*)vg0;
      vr1 = *(const bf16x8*)vg1;
      vg0 += 64; vg1 += 64;
    }
    // prefetch next tile's ksq/mbias
    float4 ks4n[4], mb4n[4];
    if (more) {
      const int ktn = (t + 1) * 64;
      #pragma unroll
      for (int c = 0; c < 4; c++) {
        ks4n[c] = *(const float4*)(ksqh + ktn + c * 16 + quad * 4);
        mb4n[c] = *(const float4*)(mbb + ktn + c * 16 + quad * 4);
      }
    }
    // S^T MFMAs from LDS K tile
    floatx4 dot[4];
    #pragma unroll
    for (int c = 0; c < 4; c++) {
      const int rbase = (c * 16 + r16) * 64;
      bf16x8 kf0 = *(const bf16x8*)(&lK[cur][rbase + sl0]);
      bf16x8 kf1 = *(const bf16x8*)(&lK[cur][rbase + sl1]);
      floatx4 a = {};
      a = __builtin_amdgcn_mfma_f32_16x16x32_bf16(kf0, qf0, a, 0, 0, 0);
      a = __builtin_amdgcn_mfma_f32_16x16x32_bf16(kf1, qf1, a, 0, 0, 0);
      dot[c] = a;
    }
    // transform to log2-domain scores; per-lane max only
    float rmax = -1e30f;
    #pragma unroll
    for (int c = 0; c < 4; c++) {
      #pragma unroll
      for (int reg = 0; reg < 4; reg++) {
        const float dd = dot[c][reg];
        const float kss = ((const float*)&ks4[c])[reg];  // has +eps
        const float mbv = ((const float*)&mb4[c])[reg];
        const float den = __builtin_fmaf(dd, -2.f, qs + kss);
        const float sc = __builtin_fmaf((dd * 1.44269504f) * dd,
                                        __builtin_amdgcn_rcpf(den), mbv);
        dot[c][reg] = sc;
        rmax = fmaxf(rmax, sc);
      }
    }
    // gated rescale (defer-max, log2 THR = 8*log2e)
    if (!__all(rmax <= mi + 11.5416f)) {
      float rg = fmaxf(rmax, __shfl_xor(rmax, 16));
      rg = fmaxf(rg, __shfl_xor(rg, 32));
      const float mnew = fmaxf(mi, rg);
      const float alpha = exp2f(mi - mnew);
      li *= alpha;
      #pragma unroll
      for (int t4 = 0; t4 < 4; t4++) {
        #pragma unroll
        for (int reg = 0; reg < 4; reg++) of[t4][reg] *= alpha;
      }
      mi = mnew;
    }
    float psum = 0.f;
    #pragma unroll
    for (int c = 0; c < 4; c++) {
      bf16x4 pk;
      #pragma unroll
      for (int reg = 0; reg < 4; reg++) {
        const float p = exp2f(dot[c][reg] - mi);  // masked: exp2(-huge)=0
        psum += p;
        pk[reg] = (bf16_t)p;
      }
      // write 8B at logical chunk 2c+(quad>>1), intra (quad&1)*4 elems, swz
      const int jw = (2 * c + (quad >> 1)) ^ pswz;
      *(bf16x4*)(myP + r16 * 64 + jw * 8 + (quad & 1) * 4) = pk;
    }
    li += psum;  // per-lane partial
    // P B-fragments: logical chunks quad and 4+quad, swizzled
    bf16x8 pf0 = *(const bf16x8*)(myP + r16 * 64 + (quad ^ pswz) * 8);
    bf16x8 pf1 = *(const bf16x8*)(myP + r16 * 64 + ((4 + quad) ^ pswz) * 8);
    // O^T += VT . P^T from single-buffered lV
    #pragma unroll
    for (int t4 = 0; t4 < 4; t4++) {
      const int rbase = (t4 * 16 + r16) * 64;
      bf16x8 vf0 = *(const bf16x8*)(&lV[rbase + sl0]);
      bf16x8 vf1 = *(const bf16x8*)(&lV[rbase + sl1]);
      of[t4] = __builtin_amdgcn_mfma_f32_16x16x32_bf16(vf0, pf0, of[t4], 0, 0, 0);
      of[t4] = __builtin_amdgcn_mfma_f32_16x16x32_bf16(vf1, pf1, of[t4], 0, 0, 0);
    }
    __syncthreads();          // barrier1: all waves done reading lV(t)
    if (more) {
      *(bf16x8*)(&lV[p0 * 8]) = vr0;          // ds_write V(t+1)
      *(bf16x8*)(&lV[(p0 + 256) * 8]) = vr1;
      __syncthreads();        // barrier2: V(t+1) visible (lgkm drain)
      #pragma unroll
      for (int c = 0; c < 4; c++) { ks4[c] = ks4n[c]; mb4[c] = mb4n[c]; }
    }
  }
  // epilogue: reduce li across the query's 4 lanes, normalize, write bf16 AO
  li += __shfl_xor(li, 16);
  li += __shfl_xor(li, 32);
  const float inv = (li > 0.f) ? __builtin_amdgcn_rcpf(li) : 0.f;
  bf16_t* aor = AO + ((size_t)(b * Lc + q0 + r16)) * Ec + h * 64;
  #pragma unroll
  for (int t4 = 0; t4 < 4; t4++) {
    bf16x4 o;
    #pragma unroll
    for (int reg = 0; reg < 4; reg++) o[reg] = (bf16_t)(of[t4][reg] * inv);
    *(bf16x4*)(aor + t4 * 16 + quad * 4) = o;
  }
}

// ---------------- launch ----------------

extern "C" void kernel_launch(void* const* d_in, const int* in_sizes, int n_in,
                              void* d_out, int out_size, void* d_ws, size_t ws_size,
                              hipStream_t stream) {
  const float* x    = (const float*)d_in[0];
  const int*   mask = (const int*)d_in[1];
  const float* Wqkv = (const float*)d_in[2];
  const float* bqkv = (const float*)d_in[3];
  const float* Wout = (const float*)d_in[4];
  const float* bout = (const float*)d_in[5];
  float* out = (float*)d_out;

  auto al = [](size_t x) { return (x + 255) & ~(size_t)255; };
  char* ws = (char*)d_ws;
  size_t off = 0;
  auto carve = [&](size_t bytes) -> char* {
    char* p = ws + off;
    off += al(bytes);
    return p;
  };
  bf16_t* WoT = (bf16_t*)carve((size_t)Ec * Ec * 2);
  bf16_t* Qb  = (bf16_t*)carve((size_t)ROWSc * Dc * 2);
  bf16_t* Kb  = (bf16_t*)carve((size_t)ROWSc * Dc * 2);
  bf16_t* VTb = (bf16_t*)carve((size_t)ROWSc * Dc * 2);
  bf16_t* AOb = (bf16_t*)carve((size_t)Mc * Ec * 2);
  float*  qsq = (float*)carve((size_t)ROWSc * 4);
  float*  ksq = (float*)carve((size_t)ROWSc * 4);
  float*  mbias = (float*)carve((size_t)Bc * Lc * 4);
  const size_t uni = off;
  bf16_t* xb  = (bf16_t*)(ws + uni);
  bf16_t* WqT = (bf16_t*)(ws + uni + al((size_t)Mc * Ec * 2));
  bf16_t* Vb  = (bf16_t*)(ws + uni + al((size_t)Mc * Ec * 2) + al((size_t)N3c * Ec * 2));
  (void)in_sizes; (void)n_in; (void)out_size; (void)ws_size;

  k_prep<<<5376, 256, 0, stream>>>(x, xb, Wqkv, WqT, Wout, WoT);
  k_gemm_qkv<<<dim3(N3c / 128, Mc / 128), 256, 0, stream>>>(xb, WqT, bqkv, Qb, Kb, Vb);
  k_prep2<<<960, 256, 0, stream>>>(Qb, Kb, mask, qsq, ksq, mbias, Vb, VTb);
  k_attn<<<dim3(ROWSc / 64), 256, 0, stream>>>(Qb, Kb, VTb, qsq, ksq, mbias, AOb);
  k_gemm_out<<<dim3(Ec / 128, Mc / 128), 256, 0, stream>>>(AOb, WoT, bout, out);
}